// Round 9
// baseline (823.596 us; speedup 1.0000x reference)
//
#include <hip/hip_runtime.h>
#include <math.h>

#define V 50257
#define D 1024
#define C 131072
#define SMOOTH 32.0f

// clang-native float4 (ext_vector_type) — required for __builtin_nontemporal_load
typedef float fx4 __attribute__((ext_vector_type(4)));

// ---------------------------------------------------------------------------
// Kernel 1: TWO cache elements per 64-lane wave (16 outstanding 16B loads).
//   ssq = sum_d (cache_h[i][d] - h_t[w][d])^2
//   atomicAdd(p[w], exp(sqrt(ssq)/SMOOTH))
// cache_h streamed once -> non-temporal; h_t gather (~2.6x reuse, 206 MB)
// left cacheable so Infinity Cache retains it.
// Block = 256 threads = 4 waves -> 8 elements/block, grid = C/8.
// ---------------------------------------------------------------------------
__global__ __launch_bounds__(256) void k_scatter(
    const float* __restrict__ h_t,
    const float* __restrict__ cache_h,
    const int* __restrict__ cache_words,
    float* __restrict__ p)
{
    const int wave = threadIdx.x >> 6;
    const int lane = threadIdx.x & 63;
    const int i0 = (blockIdx.x << 3) + (wave << 1);   // 2 consecutive elements
    const int i1 = i0 + 1;

    const int w0 = cache_words[i0];
    const int w1 = cache_words[i1];
    const fx4* ch0 = (const fx4*)(cache_h + (size_t)i0 * D);
    const fx4* ch1 = (const fx4*)(cache_h + (size_t)i1 * D);
    const fx4* ht0 = (const fx4*)(h_t + (size_t)w0 * D);
    const fx4* ht1 = (const fx4*)(h_t + (size_t)w1 * D);

    float ssq0 = 0.0f, ssq1 = 0.0f;
#pragma unroll
    for (int k = 0; k < 4; ++k) {
        fx4 a0 = __builtin_nontemporal_load(&ch0[lane + (k << 6)]);  // streaming
        fx4 b0 = ht0[lane + (k << 6)];                               // cached (reused)
        fx4 a1 = __builtin_nontemporal_load(&ch1[lane + (k << 6)]);
        fx4 b1 = ht1[lane + (k << 6)];
        fx4 d0 = a0 - b0;
        fx4 d1 = a1 - b1;
        ssq0 += d0.x * d0.x + d0.y * d0.y + d0.z * d0.z + d0.w * d0.w;
        ssq1 += d1.x * d1.x + d1.y * d1.y + d1.z * d1.z + d1.w * d1.w;
    }
    // two interleaved 64-lane butterfly reduces
#pragma unroll
    for (int off = 32; off > 0; off >>= 1) {
        ssq0 += __shfl_xor(ssq0, off, 64);
        ssq1 += __shfl_xor(ssq1, off, 64);
    }
    if (lane == 0)
        atomicAdd(&p[w0], expf(sqrtf(ssq0) * (1.0f / SMOOTH)));
    if (lane == 32)
        atomicAdd(&p[w1], expf(sqrtf(ssq1) * (1.0f / SMOOTH)));
}

// ---------------------------------------------------------------------------
// Kernel 2: fused log-softmax over p[V] (200 KB, L2-resident), ONE block.
//   out[v] = p[v] - max - log(sum exp(p - max))
// ---------------------------------------------------------------------------
__global__ __launch_bounds__(1024) void k_logsoftmax(
    const float* __restrict__ p, float* __restrict__ out)
{
    __shared__ float red[16];
    __shared__ float bcast;
    const int tid = threadIdx.x;

    // pass 1: block max (p >= 0, empty bins are 0)
    float lm = 0.0f;
    for (int v = tid; v < V; v += 1024) lm = fmaxf(lm, p[v]);
#pragma unroll
    for (int off = 32; off > 0; off >>= 1)
        lm = fmaxf(lm, __shfl_xor(lm, off, 64));
    if ((tid & 63) == 0) red[tid >> 6] = lm;
    __syncthreads();
    if (tid == 0) {
        float mm = red[0];
        for (int k = 1; k < 16; ++k) mm = fmaxf(mm, red[k]);
        bcast = mm;
    }
    __syncthreads();
    const float m = bcast;

    // pass 2: block sum of exp(p - m)
    float ls = 0.0f;
    for (int v = tid; v < V; v += 1024) ls += expf(p[v] - m);
#pragma unroll
    for (int off = 32; off > 0; off >>= 1)
        ls += __shfl_xor(ls, off, 64);
    if ((tid & 63) == 0) red[tid >> 6] = ls;
    __syncthreads();
    if (tid == 0) {
        float S = 0.0f;
        for (int k = 0; k < 16; ++k) S += red[k];
        bcast = m + logf(S);
    }
    __syncthreads();
    const float shift = bcast;

    // pass 3: write
    for (int v = tid; v < V; v += 1024) out[v] = p[v] - shift;
}

extern "C" void kernel_launch(void* const* d_in, const int* in_sizes, int n_in,
                              void* d_out, int out_size, void* d_ws, size_t ws_size,
                              hipStream_t stream)
{
    const float* h_t         = (const float*)d_in[0];   // [V, D]
    const float* cache_h     = (const float*)d_in[1];   // [C, D]
    const int*   cache_words = (const int*)d_in[2];     // [C]
    float* out = (float*)d_out;                         // [V]

    // workspace: p[V] floats only (m, S now live in the fused epilogue)
    float* p = (float*)d_ws;

    (void)hipMemsetAsync(p, 0, (size_t)V * sizeof(float), stream);

    k_scatter<<<C / 8, 256, 0, stream>>>(h_t, cache_h, cache_words, p);

    k_logsoftmax<<<1, 1024, 0, stream>>>(p, out);
}